// Round 1
// baseline (496.289 us; speedup 1.0000x reference)
//
#include <hip/hip_runtime.h>
#include <stdint.h>

// SpikingNeuralNetwork: B=32, S=4096, D=512, H=256, OUT=128
// Fused single-kernel producer->consumer pipeline.
//
// Producers (blocks 0..511): each handles 2 float4-rows of currents
//   (f = blockIdx + 512*g, g=0..1), i.e. 4 s-rows per pass: batch-mean of
//   x over B (HBM-bound, 268 MB total) then GEMV projection to H=256.
//   After each pass: barrier (drains stores to L2), thread 0 issues an
//   agent RELEASE fence (buffer_wbl2 -> coherence point) + atomicAdd on the
//   chunk flag. Pass ordering means chunks 0..31 are ready at ~T_A/2 and
//   32..63 at ~T_A, so the scan pipelines behind the projection.
// Consumers (blocks 512..515, 1 wave each): LIF scan, one neuron chain per
//   lane. Per chunk: spin on atomicAdd(&flags[c],0) (coherent RMW — no
//   stale-L2 poll risk), agent ACQUIRE fence (buffer_inv — graph replay
//   leaves stale cur4 lines in this XCD's L2 from the previous iteration),
//   then 16B global_load_lds DMA into double-buffered LDS. vmcnt(16) after
//   issuing chunk c+1 waits only for chunk c's 16 oldest loads (in-order
//   retirement), keeping the prefetch in flight.
// Flags live in ws at +4MB and are zeroed by hipMemsetAsync (ws is poisoned
//   between iterations); d_out likewise memset (consumers atomicAdd into it).
// Accumulation orders / LIF recurrence / epilogue are kept bit-identical to
//   the previous 2-kernel version (absmax 0.0).

#define S_LEN 4096
#define D_DIM 512
#define H_DIM 256
#define O_DIM 128
#define B_SZ  32

#define NPROD 512               // producer blocks
#define NCONS 4                 // consumer blocks (64 neurons each)
#define FPB   2                 // float4-rows (passes) per producer block
#define CH    64                // scan steps per chunk
#define NCH   (S_LEN / CH)      // 64 chunks
#define ROWS  (CH / 4)          // 16 float4-rows per chunk
#define FLAG_GOAL 16u           // float4-rows per chunk

typedef const __attribute__((address_space(1))) void  glob_void;
typedef       __attribute__((address_space(3))) void  lds_void;

// One LIF step, fused form (bit-exact to reference):
#define LIF_STEP(IC) {                          \
    float ict = sp2 ? 0.f : (IC);               \
    float tt  = fmaf(0.95f, u, ict);            \
    u   = sp1 ? 0.f : tt;                       \
    bool sp = (u >= 1.0f);                      \
    cnt += sp ? 1 : 0;                          \
    sp2 = sp1; sp1 = sp; }

#define ACC4(A, V) { A.x += V.x; A.y += V.y; A.z += V.z; A.w += V.w; }

__global__ __launch_bounds__(256, 2)
void snn_fused(const float4* __restrict__ x4,
               const float*  __restrict__ iw,
               const float*  __restrict__ hw,
               float4*       __restrict__ cur4,
               uint32_t*     __restrict__ flags,
               float*        __restrict__ out) {
    // LDS overlay: producers use first 8 KB as xm[4][128] float4;
    // consumers use 2x16 KB DMA double-buffer + 256 B spike counts.
    __shared__ __attribute__((aligned(16))) char smem[2 * ROWS * 64 * 16 + 256];
    const int t = threadIdx.x;

    if (blockIdx.x < NPROD) {
        // ------------------------- producer -------------------------
        float4* xm = (float4*)smem;            // [4][128] float4
        const int r2 = t >> 7;                 // 0..1: this thread's row pair
        const int d4 = t & 127;
        const int h  = t;
        const float inv = 1.0f / (float)B_SZ;
        const size_t bstr = (size_t)S_LEN * (D_DIM / 4);   // batch stride (float4)

        for (int g = 0; g < FPB; ++g) {
            const int f  = blockIdx.x + NPROD * g;   // float4-row 0..1023
            const int s0 = 4 * f;

            // Stage 1: batch-mean of rows s0+r2 and s0+r2+2 (ascending-b order,
            // identical accumulation sequence to the previous kernel).
            float4 a0 = make_float4(0.f, 0.f, 0.f, 0.f);
            float4 a1 = make_float4(0.f, 0.f, 0.f, 0.f);
            const float4* xb = x4 + (size_t)(s0 + r2) * (D_DIM / 4) + d4;
            for (int b = 0; b < B_SZ; b += 4) {
                const float4* p = xb + (size_t)b * bstr;
                float4 v00 = p[0],            v01 = p[2 * (D_DIM / 4)];
                float4 v10 = p[bstr],         v11 = p[bstr + 2 * (D_DIM / 4)];
                float4 v20 = p[2 * bstr],     v21 = p[2 * bstr + 2 * (D_DIM / 4)];
                float4 v30 = p[3 * bstr],     v31 = p[3 * bstr + 2 * (D_DIM / 4)];
                ACC4(a0, v00); ACC4(a0, v10); ACC4(a0, v20); ACC4(a0, v30);
                ACC4(a1, v01); ACC4(a1, v11); ACC4(a1, v21); ACC4(a1, v31);
            }
            a0.x *= inv; a0.y *= inv; a0.z *= inv; a0.w *= inv;
            a1.x *= inv; a1.y *= inv; a1.z *= inv; a1.w *= inv;
            xm[r2 * (D_DIM / 4) + d4]       = a0;   // row s0+r2
            xm[(r2 + 2) * (D_DIM / 4) + d4] = a1;   // row s0+r2+2
            __syncthreads();

            // Stage 2: currents[s0+r][h] = sum_d xm[r][d] * W_in[d][h]; thread = h.
            float acc2[4] = {0.f, 0.f, 0.f, 0.f};
            for (int d4i = 0; d4i < D_DIM / 4; ++d4i) {
                const int d = d4i * 4;
                float w0 = iw[(d + 0) * H_DIM + h];
                float w1 = iw[(d + 1) * H_DIM + h];
                float w2 = iw[(d + 2) * H_DIM + h];
                float w3 = iw[(d + 3) * H_DIM + h];
                #pragma unroll
                for (int r = 0; r < 4; ++r) {
                    float4 xv = xm[r * (D_DIM / 4) + d4i];   // same-addr broadcast
                    acc2[r] += xv.x * w0 + xv.y * w1 + xv.z * w2 + xv.w * w3;
                }
            }
            cur4[(size_t)f * H_DIM + h] =
                make_float4(acc2[0], acc2[1], acc2[2], acc2[3]);

            // Publish: barrier drains every wave's stores (vmcnt(0) before
            // s_barrier => data in L2), release fence writes L2 back to the
            // coherence point, then flag the chunk.
            __syncthreads();
            if (t == 0) {
                __builtin_amdgcn_fence(__ATOMIC_RELEASE, "agent");
                atomicAdd(&flags[f >> 4], 1u);
            }
        }
        return;
    }

    // ------------------------- consumer -------------------------
    if (t >= 64) return;                       // 1 wave per consumer block
    float4 (*lbuf)[ROWS * 64] = (float4 (*)[ROWS * 64])smem;
    float* cl = (float*)(smem + 2 * ROWS * 64 * 16);
    const int lane  = t;
    const int hbase = (int)(blockIdx.x - NPROD) * 64;

    auto wait_chunk = [&](int c) {
        if (lane == 0) {
            while (atomicAdd(&flags[c], 0u) < FLAG_GOAL)
                __builtin_amdgcn_s_sleep(2);
        }
        // Invalidate stale L1/L2 lines (prev graph iteration / other XCD data)
        // before any load of this chunk.
        __builtin_amdgcn_fence(__ATOMIC_ACQUIRE, "agent");
    };
    auto stage = [&](int c) {
        #pragma unroll
        for (int r = 0; r < ROWS; ++r) {
            const float4* g = cur4 + (size_t)(c * ROWS + r) * H_DIM + hbase + lane;
            __builtin_amdgcn_global_load_lds((glob_void*)g,
                                             (lds_void*)&lbuf[c & 1][r * 64 + lane],
                                             16, 0, 0);
        }
    };

    wait_chunk(0);
    stage(0);

    float u = 0.f;
    int   cnt = 0;
    bool  sp1 = false, sp2 = false;

    for (int c = 0; c < NCH; ++c) {
        if (c + 1 < NCH) {
            wait_chunk(c + 1);                 // poll drains vmcnt as a side effect
            stage(c + 1);
            // Wait only for chunk c's 16 oldest DMAs (in-order retirement);
            // chunk c+1's 16 stay in flight under this chunk's scan.
            asm volatile("s_waitcnt vmcnt(16)" ::: "memory");
        } else {
            asm volatile("s_waitcnt vmcnt(0)" ::: "memory");
        }
        const float4* lb = lbuf[c & 1];
        float4 v[ROWS];
        #pragma unroll
        for (int r = 0; r < ROWS; ++r) v[r] = lb[r * 64 + lane];
        __builtin_amdgcn_sched_barrier(0);     // keep reads out of the serial chain

        #pragma unroll
        for (int r = 0; r < ROWS; ++r) {
            LIF_STEP(v[r].x); LIF_STEP(v[r].y); LIF_STEP(v[r].z); LIF_STEP(v[r].w);
        }
    }

    // Epilogue: partial out_mean over this block's 64 neurons, atomic-combined.
    __syncthreads();
    cl[lane] = (float)cnt;
    __syncthreads();
    float a0 = 0.f, a1 = 0.f;
    #pragma unroll 8
    for (int k = 0; k < 64; ++k) {
        float c = cl[k];
        const float* w = hw + (size_t)(hbase + k) * O_DIM;
        a0 = fmaf(c, w[lane], a0);
        a1 = fmaf(c, w[lane + 64], a1);
    }
    a0 *= (1.0f / (float)S_LEN);
    a1 *= (1.0f / (float)S_LEN);
    for (int b = 0; b < B_SZ; ++b) {
        atomicAdd(out + b * O_DIM + lane,      a0);
        atomicAdd(out + b * O_DIM + lane + 64, a1);
    }
}

extern "C" void kernel_launch(void* const* d_in, const int* in_sizes, int n_in,
                              void* d_out, int out_size, void* d_ws, size_t ws_size,
                              hipStream_t stream) {
    const float4* x4 = (const float4*)d_in[0];       // [32,4096,512] f32
    const float*  iw = (const float*) d_in[1];       // [512,256] f32
    const float*  hw = (const float*) d_in[2];       // [256,128] f32
    float* out   = (float*)d_out;                    // [32,128] f32
    float4* cur4 = (float4*)d_ws;                    // [1024][256] float4 = 4 MB
    uint32_t* flags = (uint32_t*)((char*)d_ws + (size_t)4 * 1024 * 1024);

    hipMemsetAsync(flags, 0, NCH * sizeof(uint32_t), stream);
    hipMemsetAsync(out,   0, B_SZ * O_DIM * sizeof(float), stream);
    hipLaunchKernelGGL(snn_fused, dim3(NPROD + NCONS), dim3(256), 0, stream,
                       x4, iw, hw, cur4, flags, out);
}

// Round 3
// 462.203 us; speedup vs baseline: 1.0737x; 1.0737x over previous
//
#include <hip/hip_runtime.h>
#include <stdint.h>

// SpikingNeuralNetwork: B=32, S=4096, D=512, H=256, OUT=128
// Fused single-kernel producer->consumer pipeline. Cross-XCD coherence via
// relaxed AGENT-scope atomic loads/stores (lower to global_load/store_dword
// with sc1 device-coherence bit) — ZERO cache-maintenance instructions
// (round-1's agent fences lowered to buffer_wbl2/buffer_inv and collapsed
// BW to 605 GB/s; round-2's inline-asm sc0/sc1 didn't compile: float4 is a
// struct, not an ext_vector, so the "v" constraint rejects it).
//
// Producers (blocks 0..255, 4 passes): pass g computes float4-rows
//   f = blockIdx + 256g (s-rows 4f..4f+3): batch-mean of x (268 MB stream,
//   mostly L3-resident across graph iterations) + GEMV projection to H=256.
//   Publish: 4 coalesced sc1 dword stores to cur[s][h], __syncthreads
//   (s_waitcnt vmcnt(0) -> stores at coherence point), then relaxed agent
//   atomicAdd on ctr[g]. Pass g done => chunks 16g..16g+15 readable.
// Consumers (blocks 256..259, 1 wave): LIF scan, one neuron chain per lane.
//   Register double buffer (2 x 64 floats); 64 relaxed agent dword loads per
//   chunk (bypass stale local L2 -> no buffer_inv); sched_barrier(0) pins the
//   issue/scan order. Polls ctr once per 16 chunks (4 polls total).
// Residency: 260 blocks <= 2 blocks/CU * 256 CUs even at VGPR<=256, so
//   consumers are co-resident from t=0 and pipeline behind the producers
//   (round-1 launched 516 blocks at 512 capacity — consumers started late).
// Deadlock-free: producers never wait; consumers only wait on producers.
// Mean/GEMV/LIF/epilogue arithmetic byte-identical to the absmax-0.0
// versions from rounds 0/1.

#define S_LEN 4096
#define D_DIM 512
#define H_DIM 256
#define O_DIM 128
#define B_SZ  32

#define NPROD 256               // producer blocks
#define NCONS 4                 // consumer blocks (64 neurons each)
#define FPB   4                 // passes per producer block (f = bid + 256g)
#define CH    64                // scan steps per chunk
#define NCH   (S_LEN / CH)      // 64 chunks

// One LIF step, fused form (bit-exact to reference):
#define LIF_STEP(IC) {                          \
    float ict = sp2 ? 0.f : (IC);               \
    float tt  = fmaf(0.95f, u, ict);            \
    u   = sp1 ? 0.f : tt;                       \
    bool sp = (u >= 1.0f);                      \
    cnt += sp ? 1 : 0;                          \
    sp2 = sp1; sp1 = sp; }

#define ACC4(A, V) { A.x += V.x; A.y += V.y; A.z += V.z; A.w += V.w; }

// Issue CH device-coherent dword loads for chunk C into register array BUF.
#define CISSUE(BUF, C) {                                                     \
    const float* p_ = csrc + (size_t)(C) * (CH * H_DIM);                     \
    _Pragma("unroll")                                                        \
    for (int r_ = 0; r_ < CH; ++r_)                                          \
        BUF[r_] = __hip_atomic_load(p_ + (size_t)r_ * H_DIM,                 \
                                    __ATOMIC_RELAXED,                        \
                                    __HIP_MEMORY_SCOPE_AGENT);              \
    __builtin_amdgcn_sched_barrier(0); }

#define CSCAN(BUF) {                                                         \
    _Pragma("unroll")                                                        \
    for (int r_ = 0; r_ < CH; ++r_) { LIF_STEP(BUF[r_]); }                   \
    __builtin_amdgcn_sched_barrier(0); }

__global__ __launch_bounds__(256, 2)
void snn_fused(const float4* __restrict__ x4,
               const float*  __restrict__ iw,
               const float*  __restrict__ hw,
               float*        __restrict__ cur,
               uint32_t*     __restrict__ ctr,
               float*        __restrict__ out) {
    // LDS: producer xm[4][128] float4 (8 KB) union consumer cl[64] (256 B).
    __shared__ __attribute__((aligned(16))) char smem[4 * 128 * 16 + 256];
    const int t = threadIdx.x;

    if (blockIdx.x < NPROD) {
        // ------------------------- producer -------------------------
        float4* xm = (float4*)smem;            // [4][128] float4
        const int r2 = t >> 7;                 // 0..1: this thread's row pair
        const int d4 = t & 127;
        const int h  = t;
        const float inv = 1.0f / (float)B_SZ;
        const size_t bstr = (size_t)S_LEN * (D_DIM / 4);   // batch stride (float4)

        for (int g = 0; g < FPB; ++g) {
            const int f  = blockIdx.x + NPROD * g;   // float4-row 0..1023
            const int s0 = 4 * f;

            // Stage 1: batch-mean of rows s0+r2 and s0+r2+2 (ascending-b order,
            // identical accumulation sequence to the verified kernels).
            float4 a0 = make_float4(0.f, 0.f, 0.f, 0.f);
            float4 a1 = make_float4(0.f, 0.f, 0.f, 0.f);
            const float4* xb = x4 + (size_t)(s0 + r2) * (D_DIM / 4) + d4;
            for (int b = 0; b < B_SZ; b += 4) {
                const float4* p = xb + (size_t)b * bstr;
                float4 v00 = p[0],            v01 = p[2 * (D_DIM / 4)];
                float4 v10 = p[bstr],         v11 = p[bstr + 2 * (D_DIM / 4)];
                float4 v20 = p[2 * bstr],     v21 = p[2 * bstr + 2 * (D_DIM / 4)];
                float4 v30 = p[3 * bstr],     v31 = p[3 * bstr + 2 * (D_DIM / 4)];
                ACC4(a0, v00); ACC4(a0, v10); ACC4(a0, v20); ACC4(a0, v30);
                ACC4(a1, v01); ACC4(a1, v11); ACC4(a1, v21); ACC4(a1, v31);
            }
            a0.x *= inv; a0.y *= inv; a0.z *= inv; a0.w *= inv;
            a1.x *= inv; a1.y *= inv; a1.z *= inv; a1.w *= inv;
            xm[r2 * (D_DIM / 4) + d4]       = a0;   // row s0+r2
            xm[(r2 + 2) * (D_DIM / 4) + d4] = a1;   // row s0+r2+2
            __syncthreads();

            // Stage 2: currents[s0+r][h] = sum_d xm[r][d] * W_in[d][h]; thread = h.
            float acc2[4] = {0.f, 0.f, 0.f, 0.f};
            for (int d4i = 0; d4i < D_DIM / 4; ++d4i) {
                const int d = d4i * 4;
                float w0 = iw[(d + 0) * H_DIM + h];
                float w1 = iw[(d + 1) * H_DIM + h];
                float w2 = iw[(d + 2) * H_DIM + h];
                float w3 = iw[(d + 3) * H_DIM + h];
                #pragma unroll
                for (int r = 0; r < 4; ++r) {
                    float4 xv = xm[r * (D_DIM / 4) + d4i];   // same-addr broadcast
                    acc2[r] += xv.x * w0 + xv.y * w1 + xv.z * w2 + xv.w * w3;
                }
            }
            // Device-coherent (sc1) write-through stores, lane-contiguous.
            {
                float* dst = cur + (size_t)s0 * H_DIM + h;
                #pragma unroll
                for (int r = 0; r < 4; ++r)
                    __hip_atomic_store(dst + (size_t)r * H_DIM, acc2[r],
                                       __ATOMIC_RELAXED, __HIP_MEMORY_SCOPE_AGENT);
            }
            // Publish: barrier drains vmcnt(0) (stores reach the coherence
            // point) AND protects xm before next pass overwrites it; then a
            // relaxed device-scope counter bump.
            __syncthreads();
            if (t == 0)
                __hip_atomic_fetch_add(&ctr[g], 1u, __ATOMIC_RELAXED,
                                       __HIP_MEMORY_SCOPE_AGENT);
        }
        return;
    }

    // ------------------------- consumer -------------------------
    if (t >= 64) return;                       // 1 wave per consumer block
    float* cl = (float*)(smem + 4 * 128 * 16);
    const int lane  = t;
    const int hbase = (int)(blockIdx.x - NPROD) * 64;
    const float* csrc = cur + hbase + lane;

    // Chunk c needs producer pass c>>4 complete (ctr[c>>4] == NPROD).
    auto wait_pass = [&](int gp) {
        if (lane == 0) {
            while (__hip_atomic_load(&ctr[gp], __ATOMIC_RELAXED,
                                     __HIP_MEMORY_SCOPE_AGENT) < (uint32_t)NPROD)
                __builtin_amdgcn_s_sleep(8);
        }
    };

    float va[CH], vb[CH];                      // register double buffer
    float u = 0.f;
    int   cnt = 0;
    bool  sp1 = false, sp2 = false;

    wait_pass(0);
    CISSUE(va, 0);
    for (int c = 0; c < NCH; c += 2) {
        CISSUE(vb, c + 1);                     // prefetch; compiler-counted waits
        CSCAN(va);
        if (c + 2 < NCH) {
            if (((c + 2) & 15) == 0) wait_pass((c + 2) >> 4);
            CISSUE(va, c + 2);
        }
        CSCAN(vb);
    }

    // Epilogue: partial out_mean over this block's 64 neurons, atomic-combined.
    __syncthreads();
    cl[lane] = (float)cnt;
    __syncthreads();
    float a0 = 0.f, a1 = 0.f;
    #pragma unroll 8
    for (int k = 0; k < 64; ++k) {
        float c = cl[k];
        const float* w = hw + (size_t)(hbase + k) * O_DIM;
        a0 = fmaf(c, w[lane], a0);
        a1 = fmaf(c, w[lane + 64], a1);
    }
    a0 *= (1.0f / (float)S_LEN);
    a1 *= (1.0f / (float)S_LEN);
    for (int b = 0; b < B_SZ; ++b) {
        atomicAdd(out + b * O_DIM + lane,      a0);
        atomicAdd(out + b * O_DIM + lane + 64, a1);
    }
}

extern "C" void kernel_launch(void* const* d_in, const int* in_sizes, int n_in,
                              void* d_out, int out_size, void* d_ws, size_t ws_size,
                              hipStream_t stream) {
    const float4* x4 = (const float4*)d_in[0];       // [32,4096,512] f32
    const float*  iw = (const float*) d_in[1];       // [512,256] f32
    const float*  hw = (const float*) d_in[2];       // [256,128] f32
    float* out = (float*)d_out;                      // [32,128] f32
    float* cur = (float*)d_ws;                       // [4096][256] f32 = 4 MB
    uint32_t* ctr = (uint32_t*)((char*)d_ws + (size_t)4 * 1024 * 1024);

    (void)hipMemsetAsync(ctr, 0, FPB * sizeof(uint32_t), stream);
    (void)hipMemsetAsync(out, 0, B_SZ * O_DIM * sizeof(float), stream);
    hipLaunchKernelGGL(snn_fused, dim3(NPROD + NCONS), dim3(256), 0, stream,
                       x4, iw, hw, cur, ctr, out);
}

// Round 4
// 448.416 us; speedup vs baseline: 1.1068x; 1.0307x over previous
//
#include <hip/hip_runtime.h>
#include <stdint.h>

// SpikingNeuralNetwork: B=32, S=4096, D=512, H=256, OUT=128
// Fused single-kernel producer->consumer pipeline. Cross-XCD coherence via
// relaxed AGENT-scope atomic loads/stores (global_load/store_dword sc1) —
// zero cache-maintenance instructions.
//
// Round-3 post-mortem: 260 blocks = 1 block/CU = 1 wave/SIMD = OccupancyPercent
// 10%, VALUBusy 12.5% -> pure latency-bound stalling (205 us vs ~50 us floor).
// This round: 1024 single-pass producer blocks (4 blocks/CU at VGPR=104 ->
// 16 waves/CU, independent blocks hide each other's stalls) + consumers moved
// to blockIdx 0..3 (first dispatch wave -> co-resident from t=0).
//
// Producers (blocks 4..1027): f = blockIdx-4 (float4-row, s-rows 4f..4f+3):
//   batch-mean of x + GEMV projection to H=256 (arithmetic byte-identical to
//   the verified absmax-0.0 kernels). Publish: 4 coalesced sc1 dword stores,
//   __syncthreads (s_waitcnt vmcnt(0) -> stores at device coherence point),
//   then relaxed agent atomicAdd on ctr[f>>6] (16 counters, one per 4-chunk
//   group, goal 64).
// Consumers (blocks 0..3, 1 wave): LIF scan, one neuron chain per lane.
//   Register double buffer (2 x 64 floats), 64 relaxed agent dword loads per
//   chunk (bypass stale local L2), sched_barrier(0) pins issue/scan order.
//   Polls once per 4 chunks (16 polls total).
// Deadlock-free: producers never wait; consumers only wait on producers; the
//   4 non-resident producer blocks (f>=1020) run after first retirements.

#define S_LEN 4096
#define D_DIM 512
#define H_DIM 256
#define O_DIM 128
#define B_SZ  32

#define NPROD 1024              // producer blocks (1 float4-row each)
#define NCONS 4                 // consumer blocks (64 neurons each), blockIdx 0..3
#define CH    64                // scan steps per chunk
#define NCH   (S_LEN / CH)      // 64 chunks
#define NGRP  16                // progress counters (4 chunks / group)
#define GOAL  64u               // float4-rows per group

// One LIF step, fused form (bit-exact to reference):
#define LIF_STEP(IC) {                          \
    float ict = sp2 ? 0.f : (IC);               \
    float tt  = fmaf(0.95f, u, ict);            \
    u   = sp1 ? 0.f : tt;                       \
    bool sp = (u >= 1.0f);                      \
    cnt += sp ? 1 : 0;                          \
    sp2 = sp1; sp1 = sp; }

#define ACC4(A, V) { A.x += V.x; A.y += V.y; A.z += V.z; A.w += V.w; }

// Issue CH device-coherent dword loads for chunk C into register array BUF.
#define CISSUE(BUF, C) {                                                     \
    const float* p_ = csrc + (size_t)(C) * (CH * H_DIM);                     \
    _Pragma("unroll")                                                        \
    for (int r_ = 0; r_ < CH; ++r_)                                          \
        BUF[r_] = __hip_atomic_load(p_ + (size_t)r_ * H_DIM,                 \
                                    __ATOMIC_RELAXED,                        \
                                    __HIP_MEMORY_SCOPE_AGENT);              \
    __builtin_amdgcn_sched_barrier(0); }

#define CSCAN(BUF) {                                                         \
    _Pragma("unroll")                                                        \
    for (int r_ = 0; r_ < CH; ++r_) { LIF_STEP(BUF[r_]); }                   \
    __builtin_amdgcn_sched_barrier(0); }

__global__ __launch_bounds__(256, 2)
void snn_fused(const float4* __restrict__ x4,
               const float*  __restrict__ iw,
               const float*  __restrict__ hw,
               float*        __restrict__ cur,
               uint32_t*     __restrict__ ctr,
               float*        __restrict__ out) {
    // LDS: producer xm[4][128] float4 (8 KB) union consumer cl[64] (256 B).
    __shared__ __attribute__((aligned(16))) char smem[4 * 128 * 16 + 256];
    const int t = threadIdx.x;

    if (blockIdx.x >= NCONS) {
        // ------------------------- producer -------------------------
        float4* xm = (float4*)smem;            // [4][128] float4
        const int r2 = t >> 7;                 // 0..1: this thread's row pair
        const int d4 = t & 127;
        const int h  = t;
        const float inv = 1.0f / (float)B_SZ;
        const size_t bstr = (size_t)S_LEN * (D_DIM / 4);   // batch stride (float4)

        const int f  = (int)blockIdx.x - NCONS;  // float4-row 0..1023
        const int s0 = 4 * f;

        // Stage 1: batch-mean of rows s0+r2 and s0+r2+2 (ascending-b order,
        // identical accumulation sequence to the verified kernels).
        float4 a0 = make_float4(0.f, 0.f, 0.f, 0.f);
        float4 a1 = make_float4(0.f, 0.f, 0.f, 0.f);
        const float4* xb = x4 + (size_t)(s0 + r2) * (D_DIM / 4) + d4;
        for (int b = 0; b < B_SZ; b += 4) {
            const float4* p = xb + (size_t)b * bstr;
            float4 v00 = p[0],            v01 = p[2 * (D_DIM / 4)];
            float4 v10 = p[bstr],         v11 = p[bstr + 2 * (D_DIM / 4)];
            float4 v20 = p[2 * bstr],     v21 = p[2 * bstr + 2 * (D_DIM / 4)];
            float4 v30 = p[3 * bstr],     v31 = p[3 * bstr + 2 * (D_DIM / 4)];
            ACC4(a0, v00); ACC4(a0, v10); ACC4(a0, v20); ACC4(a0, v30);
            ACC4(a1, v01); ACC4(a1, v11); ACC4(a1, v21); ACC4(a1, v31);
        }
        a0.x *= inv; a0.y *= inv; a0.z *= inv; a0.w *= inv;
        a1.x *= inv; a1.y *= inv; a1.z *= inv; a1.w *= inv;
        xm[r2 * (D_DIM / 4) + d4]       = a0;   // row s0+r2
        xm[(r2 + 2) * (D_DIM / 4) + d4] = a1;   // row s0+r2+2
        __syncthreads();

        // Stage 2: currents[s0+r][h] = sum_d xm[r][d] * W_in[d][h]; thread = h.
        float acc2[4] = {0.f, 0.f, 0.f, 0.f};
        for (int d4i = 0; d4i < D_DIM / 4; ++d4i) {
            const int d = d4i * 4;
            float w0 = iw[(d + 0) * H_DIM + h];
            float w1 = iw[(d + 1) * H_DIM + h];
            float w2 = iw[(d + 2) * H_DIM + h];
            float w3 = iw[(d + 3) * H_DIM + h];
            #pragma unroll
            for (int r = 0; r < 4; ++r) {
                float4 xv = xm[r * (D_DIM / 4) + d4i];   // same-addr broadcast
                acc2[r] += xv.x * w0 + xv.y * w1 + xv.z * w2 + xv.w * w3;
            }
        }
        // Device-coherent (sc1) write-through stores, lane-contiguous.
        {
            float* dst = cur + (size_t)s0 * H_DIM + h;
            #pragma unroll
            for (int r = 0; r < 4; ++r)
                __hip_atomic_store(dst + (size_t)r * H_DIM, acc2[r],
                                   __ATOMIC_RELAXED, __HIP_MEMORY_SCOPE_AGENT);
        }
        // Publish: barrier drains vmcnt(0) (all threads' stores at the
        // coherence point), then a relaxed device-scope counter bump.
        __syncthreads();
        if (t == 0)
            __hip_atomic_fetch_add(&ctr[f >> 6], 1u, __ATOMIC_RELAXED,
                                   __HIP_MEMORY_SCOPE_AGENT);
        return;
    }

    // ------------------------- consumer -------------------------
    if (t >= 64) return;                       // 1 wave per consumer block
    float* cl = (float*)(smem + 4 * 128 * 16);
    const int lane  = t;
    const int hbase = (int)blockIdx.x * 64;
    const float* csrc = cur + hbase + lane;

    // Chunk c needs its 4-chunk group's 64 float4-rows published.
    auto wait_grp = [&](int c) {
        if ((c & 3) != 0) return;
        const int gi = c >> 2;
        if (lane == 0) {
            while (__hip_atomic_load(&ctr[gi], __ATOMIC_RELAXED,
                                     __HIP_MEMORY_SCOPE_AGENT) < GOAL)
                __builtin_amdgcn_s_sleep(8);
        }
    };

    float va[CH], vb[CH];                      // register double buffer
    float u = 0.f;
    int   cnt = 0;
    bool  sp1 = false, sp2 = false;

    wait_grp(0);
    CISSUE(va, 0);
    for (int c = 0; c < NCH; c += 2) {
        CISSUE(vb, c + 1);                     // same 4-group as c: no poll needed
        CSCAN(va);
        if (c + 2 < NCH) {
            wait_grp(c + 2);                   // polls only at 4-chunk boundary
            CISSUE(va, c + 2);
        }
        CSCAN(vb);
    }

    // Epilogue: partial out_mean over this block's 64 neurons, atomic-combined.
    __syncthreads();
    cl[lane] = (float)cnt;
    __syncthreads();
    float a0 = 0.f, a1 = 0.f;
    #pragma unroll 8
    for (int k = 0; k < 64; ++k) {
        float c = cl[k];
        const float* w = hw + (size_t)(hbase + k) * O_DIM;
        a0 = fmaf(c, w[lane], a0);
        a1 = fmaf(c, w[lane + 64], a1);
    }
    a0 *= (1.0f / (float)S_LEN);
    a1 *= (1.0f / (float)S_LEN);
    for (int b = 0; b < B_SZ; ++b) {
        atomicAdd(out + b * O_DIM + lane,      a0);
        atomicAdd(out + b * O_DIM + lane + 64, a1);
    }
}

extern "C" void kernel_launch(void* const* d_in, const int* in_sizes, int n_in,
                              void* d_out, int out_size, void* d_ws, size_t ws_size,
                              hipStream_t stream) {
    const float4* x4 = (const float4*)d_in[0];       // [32,4096,512] f32
    const float*  iw = (const float*) d_in[1];       // [512,256] f32
    const float*  hw = (const float*) d_in[2];       // [256,128] f32
    float* out = (float*)d_out;                      // [32,128] f32
    float* cur = (float*)d_ws;                       // [4096][256] f32 = 4 MB
    uint32_t* ctr = (uint32_t*)((char*)d_ws + (size_t)4 * 1024 * 1024);

    (void)hipMemsetAsync(ctr, 0, NGRP * sizeof(uint32_t), stream);
    (void)hipMemsetAsync(out, 0, B_SZ * O_DIM * sizeof(float), stream);
    hipLaunchKernelGGL(snn_fused, dim3(NCONS + NPROD), dim3(256), 0, stream,
                       x4, iw, hw, cur, ctr, out);
}